// Round 10
// baseline (136.134 us; speedup 1.0000x reference)
//
#include <hip/hip_runtime.h>

#define NB    32
#define NP    65536
#define SZ    64
#define SZ3   (SZ * SZ * SZ)     // 262144
#define KS    21
#define HALF  10
#define NBIN  65                 // plane bins: i2 in [-1, 63] -> bin i2+1
#define CAP   2048               // fixed bin capacity (max expected ~1400)
#define FXS   960.0f             // fixed-point scale; (65+2)*960 = 64320 < 65535

typedef _Float16 half8_t __attribute__((ext_vector_type(8)));
typedef _Float16 half4_t __attribute__((ext_vector_type(4)));
typedef float    f32x4_t __attribute__((ext_vector_type(4)));

// XOR-swizzled tile address: 65 rows x 64 cols of f16, 16B-chunk swizzle.
__device__ __forceinline__ int swz(int row, int col) {
    return (row << 6) + ((((col >> 3) ^ (row & 7))) << 3) + (col & 7);
}

// Normalized Gaussian taps (sigma=3) into registers
__device__ __forceinline__ void weights_reg(float* w) {
    float sum = 0.0f;
#pragma unroll
    for (int k = 0; k < KS; ++k) {
        float d = (float)k - (float)HALF;
        w[k] = expf(-d * d / 18.0f);
        sum += w[k];
    }
#pragma unroll
    for (int k = 0; k < KS; ++k) w[k] /= sum;
}

__device__ __forceinline__ void fma4(float4& a, float t, const float4& v) {
    a.x = fmaf(t, v.x, a.x); a.y = fmaf(t, v.y, a.y);
    a.z = fmaf(t, v.z, a.z); a.w = fmaf(t, v.w, a.w);
}

__device__ __forceinline__ unsigned pack_fx(float g) {
    float c = fminf(fmaxf(g, -2.0f), 65.0f);
    return (unsigned)__float2uint_rn((c + 2.0f) * FXS);
}

// ---- 1. fill fixed-capacity bins (packed u16x4), per-wave histograms ----
__global__ void fill_kernel(const float* __restrict__ pc,
                            const float* __restrict__ rot,
                            int* __restrict__ cur,
                            uint2* __restrict__ binned,
                            _Float16* __restrict__ Gg) {
    __shared__ int h[4][NBIN];
    __shared__ int woff[4][NBIN];
    __shared__ int lbase[NBIN];
    int base = blockIdx.x * 1024;          // 4 points/thread, block within one batch
    int b = base >> 16;
    int wv = threadIdx.x >> 6;
    for (int i = threadIdx.x; i < 4 * NBIN; i += 256) h[i / NBIN][i % NBIN] = 0;
    __syncthreads();
    const float* R = rot + b * 9;
    const float4* p4 = (const float4*)(pc + (size_t)base * 3);
    float4 f0 = p4[threadIdx.x * 3 + 0];
    float4 f1 = p4[threadIdx.x * 3 + 1];
    float4 f2 = p4[threadIdx.x * 3 + 2];
    float px[4] = {f0.x, f0.w, f1.z, f2.y};
    float py[4] = {f0.y, f1.x, f1.w, f2.z};
    float pz[4] = {f0.z, f1.y, f2.x, f2.w};
    uint2 pk[4];
    int bin[4], lpos[4];
#pragma unroll
    for (int j = 0; j < 4; ++j) {
        float g0 = (R[0] * px[j] + R[1] * py[j] + R[2] * pz[j] + 0.5f) * 63.0f;
        float g1 = (R[3] * px[j] + R[4] * py[j] + R[5] * pz[j] + 0.5f) * 63.0f;
        float g2 = (R[6] * px[j] + R[7] * py[j] + R[8] * pz[j] + 0.5f) * 63.0f;
        int i2 = (int)floorf(g2);
        bin[j] = (i2 >= -1 && i2 <= 63) ? i2 + 1 : -1;
        pk[j] = make_uint2(pack_fx(g0) | (pack_fx(g1) << 16), pack_fx(g2));
        if (bin[j] >= 0) lpos[j] = atomicAdd(&h[wv][bin[j]], 1);
    }
    __syncthreads();
    if (threadIdx.x < NBIN) {
        int t = threadIdx.x;
        int s0 = h[0][t], s1 = h[1][t], s2 = h[2][t], s3 = h[3][t];
        int tot = s0 + s1 + s2 + s3;
        lbase[t] = tot ? atomicAdd(&cur[b * NBIN + t], tot) : 0;
        woff[0][t] = 0; woff[1][t] = s0; woff[2][t] = s0 + s1; woff[3][t] = s0 + s1 + s2;
    }
    __syncthreads();
#pragma unroll
    for (int j = 0; j < 4; ++j)
        if (bin[j] >= 0) {
            int pos = lbase[bin[j]] + woff[wv][bin[j]] + lpos[j];
            if (pos < CAP)
                binned[(size_t)(b * NBIN + bin[j]) * CAP + pos] = pk[j];
        }
    // G[o][k] = g[o-k+10] (zero outside band), row-major stride 64
    if (blockIdx.x == 0) {
        float w[KS];
        weights_reg(w);
        for (int i = threadIdx.x; i < 4096; i += 256) {
            int d = (i >> 6) - (i & 63) + HALF;
            Gg[i] = ((unsigned)d < (unsigned)KS) ? (_Float16)w[d] : (_Float16)0.0f;
        }
    }
}

// ---- 2. MFMA splat + clip + x-blur + y-blur. TWO WAVES per (b,z) plane. ----
// Each wave scatters alternating chunks into its own tile pair; wave 1 stages
// its partial C as f32 (stride-65, conflict-free) in its dead tiles; wave 0
// merges and runs the blur GEMMs. f16 output volume.
__global__ void __launch_bounds__(128) splat_blur(const uint2* __restrict__ binned,
                                                  const int* __restrict__ cur,
                                                  const _Float16* __restrict__ Gg,
                                                  _Float16* __restrict__ vox) {
    __shared__ __align__(16) _Float16 tiles[2][2][65 * 64];   // 33280 B total
    int tid = threadIdx.x;
    int wv = tid >> 6, lane = tid & 63;
    int b = blockIdx.x >> 6, z = blockIdx.x & 63;
    int q = lane >> 4, c = lane & 15;
    _Float16* Ay = tiles[wv][0];
    _Float16* Bx = tiles[wv][1];

    {   // zero own tiles (wave-local)
        int4 z4 = {0, 0, 0, 0};
        int4* a4 = (int4*)tiles[wv];
        for (int i = lane; i < 2 * 65 * 64 * 2 / 16; i += 64) a4[i] = z4;
    }

    // G fragments (wave 0 only needs them; one pattern serves both blur passes)
    half8_t gf[4][2];
    if (wv == 0) {
#pragma unroll
        for (int ni = 0; ni < 4; ++ni)
#pragma unroll
            for (int h = 0; h < 2; ++h)
                gf[ni][h] = *(const half8_t*)&Gg[(ni * 16 + c) * 64 + h * 32 + q * 8];
    }

    // plane z consumes bins i2=z-1 (idx z) and i2=z (idx z+1)
    int c0 = min(cur[b * NBIN + z],     CAP);
    int c1 = min(cur[b * NBIN + z + 1], CAP);
    const uint2* s0 = binned + (size_t)(b * NBIN + z) * CAP;
    const uint2* s1 = binned + (size_t)(b * NBIN + z + 1) * CAP;
    int n = c0 + c1;

    f32x4_t acc[4][4];
#pragma unroll
    for (int mi = 0; mi < 4; ++mi)
#pragma unroll
        for (int ni = 0; ni < 4; ++ni) acc[mi][ni] = (f32x4_t){0.f, 0.f, 0.f, 0.f};

    int iters = (n + 63) >> 6;
    uint2 nxt = make_uint2(0u, 0u);                 // decodes to gz=-2 -> az=0
    {
        int i0g = wv * 64 + lane;
        if (i0g < n) nxt = (i0g < c0) ? s0[i0g] : s1[i0g - c0];
    }
    for (int it = wv; it < iters; it += 2) {
        uint2 pk = nxt;
        int ni2 = (it + 2) * 64 + lane;             // prefetch own next chunk
        nxt = make_uint2(0u, 0u);
        if (ni2 < n) nxt = (ni2 < c0) ? s0[ni2] : s1[ni2 - c0];

        float gx = (float)(pk.x & 0xffffu) * (1.0f / FXS) - 2.0f;
        float gy = (float)(pk.x >> 16)     * (1.0f / FXS) - 2.0f;
        float gz = (float)(pk.y & 0xffffu) * (1.0f / FXS) - 2.0f;
        float f0 = floorf(gx), f1 = floorf(gy);
        int   i0 = (int)f0,    i1 = (int)f1;
        float r0 = gx - f0,    r1f = gy - f1;
        float az = fmaxf(0.0f, 1.0f - fabsf(gz - (float)z));
        int ylo = ((unsigned)i1       < 64u) ? i1       : 64;
        int yhi = ((unsigned)(i1 + 1) < 64u) ? (i1 + 1) : 64;
        int xlo = ((unsigned)i0       < 64u) ? i0       : 64;
        int xhi = ((unsigned)(i0 + 1) < 64u) ? (i0 + 1) : 64;
        Ay[swz(ylo, lane)] = (_Float16)(az * (1.0f - r1f));
        Ay[swz(yhi, lane)] = (_Float16)(az * r1f);
        Bx[swz(xlo, lane)] = (_Float16)(1.0f - r0);
        Bx[swz(xhi, lane)] = (_Float16)r0;
#pragma unroll
        for (int h = 0; h < 2; ++h) {
            half8_t af[4], bf[4];
#pragma unroll
            for (int mi = 0; mi < 4; ++mi)
                af[mi] = *(const half8_t*)&Ay[swz(mi * 16 + c, h * 32 + q * 8)];
#pragma unroll
            for (int ni = 0; ni < 4; ++ni)
                bf[ni] = *(const half8_t*)&Bx[swz(ni * 16 + c, h * 32 + q * 8)];
#pragma unroll
            for (int mi = 0; mi < 4; ++mi)
#pragma unroll
                for (int ni = 0; ni < 4; ++ni)
                    acc[mi][ni] = __builtin_amdgcn_mfma_f32_16x16x32_f16(
                        af[mi], bf[ni], acc[mi][ni], 0, 0, 0);
        }
        // re-zero exactly what we wrote (after frag reads; wave-ordered)
        Ay[swz(ylo, lane)] = (_Float16)0.0f;
        Ay[swz(yhi, lane)] = (_Float16)0.0f;
        Bx[swz(xlo, lane)] = (_Float16)0.0f;
        Bx[swz(xhi, lane)] = (_Float16)0.0f;
    }

    // wave 1 stages its partial C as f32 (stride 65 -> conflict-free), exits
    asm volatile("" ::: "memory");
    float* Cst = (float*)tiles[1];                   // 64*65*4 = 16640 B, exact fit
    if (wv == 1) {
#pragma unroll
        for (int mi = 0; mi < 4; ++mi)
#pragma unroll
            for (int ni = 0; ni < 4; ++ni)
#pragma unroll
                for (int r = 0; r < 4; ++r)
                    Cst[(mi * 16 + q * 4 + r) * 65 + ni * 16 + c] = acc[mi][ni][r];
    }
    __syncthreads();
    if (wv == 1) return;

    // wave 0: merge, clip -> f16 plane P, then blur GEMMs
#pragma unroll
    for (int mi = 0; mi < 4; ++mi)
#pragma unroll
        for (int ni = 0; ni < 4; ++ni)
#pragma unroll
            for (int r = 0; r < 4; ++r)
                acc[mi][ni][r] += Cst[(mi * 16 + q * 4 + r) * 65 + ni * 16 + c];

    _Float16* P = Ay;                                // overlay: tiles dead now
    _Float16* T = Bx;
#pragma unroll
    for (int mi = 0; mi < 4; ++mi)
#pragma unroll
        for (int ni = 0; ni < 4; ++ni)
#pragma unroll
            for (int r = 0; r < 4; ++r)
                P[swz(mi * 16 + q * 4 + r, ni * 16 + c)] =
                    (_Float16)fminf(fmaxf(acc[mi][ni][r], 0.0f), 1.0f);
    asm volatile("" ::: "memory");

    // pass1: Cx[y][xo] = sum_k P[y][k] * G[xo][k]
    f32x4_t a2[4][4];
#pragma unroll
    for (int mi = 0; mi < 4; ++mi)
#pragma unroll
        for (int ni = 0; ni < 4; ++ni) a2[mi][ni] = (f32x4_t){0.f, 0.f, 0.f, 0.f};
#pragma unroll
    for (int h = 0; h < 2; ++h) {
        half8_t af[4];
#pragma unroll
        for (int mi = 0; mi < 4; ++mi)
            af[mi] = *(const half8_t*)&P[swz(mi * 16 + c, h * 32 + q * 8)];
#pragma unroll
        for (int mi = 0; mi < 4; ++mi)
#pragma unroll
            for (int ni = 0; ni < 4; ++ni)
                a2[mi][ni] = __builtin_amdgcn_mfma_f32_16x16x32_f16(
                    af[mi], gf[ni][h], a2[mi][ni], 0, 0, 0);
    }
    asm volatile("" ::: "memory");

    // transpose to T[x][y] (f16), packed b64 writes
#pragma unroll
    for (int mi = 0; mi < 4; ++mi)
#pragma unroll
        for (int ni = 0; ni < 4; ++ni) {
            half4_t pkd;
#pragma unroll
            for (int r = 0; r < 4; ++r) pkd[r] = (_Float16)a2[mi][ni][r];
            *(half4_t*)&T[swz(ni * 16 + c, mi * 16 + q * 4)] = pkd;
        }
    asm volatile("" ::: "memory");

    // pass2: out[yo][x] = sum_k G[yo][k] * T[x][k]
    f32x4_t a3[4][4];
#pragma unroll
    for (int mi = 0; mi < 4; ++mi)
#pragma unroll
        for (int ni = 0; ni < 4; ++ni) a3[mi][ni] = (f32x4_t){0.f, 0.f, 0.f, 0.f};
#pragma unroll
    for (int h = 0; h < 2; ++h) {
        half8_t bf[4];
#pragma unroll
        for (int ni = 0; ni < 4; ++ni)
            bf[ni] = *(const half8_t*)&T[swz(ni * 16 + c, h * 32 + q * 8)];
#pragma unroll
        for (int mi = 0; mi < 4; ++mi)
#pragma unroll
            for (int ni = 0; ni < 4; ++ni)
                a3[mi][ni] = __builtin_amdgcn_mfma_f32_16x16x32_f16(
                    gf[mi][h], bf[ni], a3[mi][ni], 0, 0, 0);
    }

    // store f16 plane
    _Float16* dst = vox + ((size_t)b << 18) + ((size_t)z << 12);
#pragma unroll
    for (int mi = 0; mi < 4; ++mi)
#pragma unroll
        for (int ni = 0; ni < 4; ++ni)
#pragma unroll
            for (int r = 0; r < 4; ++r)
                dst[((mi * 16 + q * 4 + r) << 6) + ni * 16 + c] = (_Float16)a3[mi][ni][r];
}

// ---- 3. fused conv along z (f16 in) + scale/clip + segmented DRC + y-flip ----
__global__ void convz_drc_kernel(const _Float16* __restrict__ in,
                                 const float* __restrict__ scale,
                                 float* __restrict__ out) {
    __shared__ float sraw[640 + SZ * SZ + 640];  // 10-row zero guards each side
    __shared__ float c[SZ * SZ];
    __shared__ float segS[4][64], segT[4][64];
    float* s = sraw + 640;
    int b = blockIdx.x >> 6, y = blockIdx.x & 63;

    for (int i = threadIdx.x; i < 640; i += 256) {
        sraw[i] = 0.0f;
        sraw[640 + SZ * SZ + i] = 0.0f;
    }
    const _Float16* base = in + ((size_t)b << 18) + (y << 6);
#pragma unroll
    for (int g = 0; g < 4; ++g) {
        int cell = g * 256 + threadIdx.x;        // 1024 half4 cells
        int z = cell >> 4, xc = (cell & 15) << 2;
        half4_t v = *(const half4_t*)&base[((size_t)z << 12) + xc];
        float4 f = make_float4((float)v[0], (float)v[1], (float)v[2], (float)v[3]);
        *(float4*)&s[(z << 6) + xc] = f;
    }
    __syncthreads();

    float w[KS];
    weights_reg(w);

    {   // z-conv: one (z-group-of-4, x-chunk) per thread, 24 b128 reads
        int z0 = (threadIdx.x >> 4) << 2;
        int xc = (threadIdx.x & 15) << 2;
        float4 a0 = {0,0,0,0}, a1 = {0,0,0,0}, a2 = {0,0,0,0}, a3 = {0,0,0,0};
#pragma unroll
        for (int d = 0; d < 24; ++d) {
            int zz = z0 - HALF + d;              // guards cover [-10, 73]
            float4 v = *(const float4*)&s[(zz << 6) + xc];
            if (d <= 20)           fma4(a0, w[d],     v);
            if (d >= 1 && d <= 21) fma4(a1, w[d - 1], v);
            if (d >= 2 && d <= 22) fma4(a2, w[d - 2], v);
            if (d >= 3)            fma4(a3, w[d - 3], v);
        }
        *(float4*)&c[((z0 + 0) << 6) + xc] = a0;
        *(float4*)&c[((z0 + 1) << 6) + xc] = a1;
        *(float4*)&c[((z0 + 2) << 6) + xc] = a2;
        *(float4*)&c[((z0 + 3) << 6) + xc] = a3;
    }
    __syncthreads();

    {   // segmented DRC march: 4 z-segments x 64 columns
        int x = threadIdx.x & 63, seg = threadIdx.x >> 6;
        float sc = scale[b];
        float trans = 1.0f, sum = 0.0f;
#pragma unroll
        for (int zz = 0; zz < 16; ++zz) {
            int z = seg * 16 + zz;
            float v = fminf(fmaxf(c[(z << 6) + x] * sc, 0.0f), 1.0f);
            sum += v * trans;
            trans *= 1.0f - v;
        }
        segS[seg][x] = sum;
        segT[seg][x] = trans;
    }
    __syncthreads();
    if (threadIdx.x < 64) {
        int x = threadIdx.x;
        float t = 1.0f, S = 0.0f;
#pragma unroll
        for (int sgi = 0; sgi < 4; ++sgi) { S += segS[sgi][x] * t; t *= segT[sgi][x]; }
        out[(b << 12) + ((63 - y) << 6) + x] = S;
    }
}

extern "C" void kernel_launch(void* const* d_in, const int* in_sizes, int n_in,
                              void* d_out, int out_size, void* d_ws, size_t ws_size,
                              hipStream_t stream) {
    const float* pc    = (const float*)d_in[0];
    const float* rot   = (const float*)d_in[1];
    const float* scale = (const float*)d_in[2];
    float* out = (float*)d_out;

    // ws: vox f16 16.8 MB | binned (fixed-cap, packed) 34.1 MB | G 8 KB | cursors 8.3 KB
    _Float16* vox    = (_Float16*)d_ws;
    uint2*    binned = (uint2*)((char*)d_ws + (size_t)NB * SZ3 * sizeof(_Float16));
    _Float16* Gg     = (_Float16*)((char*)binned + (size_t)NB * NBIN * CAP * sizeof(uint2));
    int*      cur    = (int*)((char*)Gg + 64 * 64 * sizeof(_Float16));

    hipMemsetAsync(cur, 0, NB * NBIN * sizeof(int), stream);

    fill_kernel     <<<NB * NP / 1024, 256, 0, stream>>>(pc, rot, cur, binned, Gg);
    splat_blur      <<<NB * SZ, 128, 0, stream>>>(binned, cur, Gg, vox);
    convz_drc_kernel<<<NB * SZ, 256, 0, stream>>>(vox, scale, out);
}

// Round 11
// 126.243 us; speedup vs baseline: 1.0784x; 1.0784x over previous
//
#include <hip/hip_runtime.h>

#define NB    32
#define NP    65536
#define SZ    64
#define SZ3   (SZ * SZ * SZ)     // 262144
#define KS    21
#define HALF  10
#define NBIN  65                 // plane bins: i2 in [-1, 63] -> bin i2+1
#define CAP   2048               // fixed bin capacity (max expected ~1400)
#define FXS   960.0f             // fixed-point scale; (65+2)*960 = 64320 < 65535

typedef _Float16 half8_t __attribute__((ext_vector_type(8)));
typedef _Float16 half4_t __attribute__((ext_vector_type(4)));
typedef float    f32x4_t __attribute__((ext_vector_type(4)));

// XOR-swizzled tile address: 65 rows x 64 cols of f16, 16B-chunk swizzle.
__device__ __forceinline__ int swz(int row, int col) {
    return (row << 6) + ((((col >> 3) ^ (row & 7))) << 3) + (col & 7);
}

// Normalized Gaussian taps (sigma=3) into registers
__device__ __forceinline__ void weights_reg(float* w) {
    float sum = 0.0f;
#pragma unroll
    for (int k = 0; k < KS; ++k) {
        float d = (float)k - (float)HALF;
        w[k] = expf(-d * d / 18.0f);
        sum += w[k];
    }
#pragma unroll
    for (int k = 0; k < KS; ++k) w[k] /= sum;
}

__device__ __forceinline__ void fma4(float4& a, float t, const float4& v) {
    a.x = fmaf(t, v.x, a.x); a.y = fmaf(t, v.y, a.y);
    a.z = fmaf(t, v.z, a.z); a.w = fmaf(t, v.w, a.w);
}

__device__ __forceinline__ unsigned pack_fx(float g) {
    float c = fminf(fmaxf(g, -2.0f), 65.0f);
    return (unsigned)__float2uint_rn((c + 2.0f) * FXS);
}

// ---- 1. fill fixed-capacity bins (packed u16x4), per-wave histograms ----
__global__ void fill_kernel(const float* __restrict__ pc,
                            const float* __restrict__ rot,
                            int* __restrict__ cur,
                            uint2* __restrict__ binned,
                            _Float16* __restrict__ Gg) {
    __shared__ int h[4][NBIN];
    __shared__ int woff[4][NBIN];
    __shared__ int lbase[NBIN];
    int base = blockIdx.x * 1024;          // 4 points/thread, block within one batch
    int b = base >> 16;
    int wv = threadIdx.x >> 6;
    for (int i = threadIdx.x; i < 4 * NBIN; i += 256) h[i / NBIN][i % NBIN] = 0;
    __syncthreads();
    const float* R = rot + b * 9;
    const float4* p4 = (const float4*)(pc + (size_t)base * 3);
    float4 f0 = p4[threadIdx.x * 3 + 0];
    float4 f1 = p4[threadIdx.x * 3 + 1];
    float4 f2 = p4[threadIdx.x * 3 + 2];
    float px[4] = {f0.x, f0.w, f1.z, f2.y};
    float py[4] = {f0.y, f1.x, f1.w, f2.z};
    float pz[4] = {f0.z, f1.y, f2.x, f2.w};
    uint2 pk[4];
    int bin[4], lpos[4];
#pragma unroll
    for (int j = 0; j < 4; ++j) {
        float g0 = (R[0] * px[j] + R[1] * py[j] + R[2] * pz[j] + 0.5f) * 63.0f;
        float g1 = (R[3] * px[j] + R[4] * py[j] + R[5] * pz[j] + 0.5f) * 63.0f;
        float g2 = (R[6] * px[j] + R[7] * py[j] + R[8] * pz[j] + 0.5f) * 63.0f;
        int i2 = (int)floorf(g2);
        bin[j] = (i2 >= -1 && i2 <= 63) ? i2 + 1 : -1;
        pk[j] = make_uint2(pack_fx(g0) | (pack_fx(g1) << 16), pack_fx(g2));
        if (bin[j] >= 0) lpos[j] = atomicAdd(&h[wv][bin[j]], 1);
    }
    __syncthreads();
    if (threadIdx.x < NBIN) {
        int t = threadIdx.x;
        int s0 = h[0][t], s1 = h[1][t], s2 = h[2][t], s3 = h[3][t];
        int tot = s0 + s1 + s2 + s3;
        lbase[t] = tot ? atomicAdd(&cur[b * NBIN + t], tot) : 0;
        woff[0][t] = 0; woff[1][t] = s0; woff[2][t] = s0 + s1; woff[3][t] = s0 + s1 + s2;
    }
    __syncthreads();
#pragma unroll
    for (int j = 0; j < 4; ++j)
        if (bin[j] >= 0) {
            int pos = lbase[bin[j]] + woff[wv][bin[j]] + lpos[j];
            if (pos < CAP)
                binned[(size_t)(b * NBIN + bin[j]) * CAP + pos] = pk[j];
        }
    // G[o][k] = g[o-k+10] (zero outside band), row-major stride 64
    if (blockIdx.x == 0) {
        float w[KS];
        weights_reg(w);
        for (int i = threadIdx.x; i < 4096; i += 256) {
            int d = (i >> 6) - (i & 63) + HALF;
            Gg[i] = ((unsigned)d < (unsigned)KS) ? (_Float16)w[d] : (_Float16)0.0f;
        }
    }
}

// ---- 2. MFMA splat + clip + x-blur + y-blur. ONE WAVE per (b,z) plane. ----
// z-shear block swizzle: blocks spaced 256 apart on one CU get z and z+32
// (256 = 0 mod 64 would otherwise give every CU 8 SAME-z planes -> 2x load
// imbalance, the R9 44-vs-25us gap). f16 output volume.
__global__ void __launch_bounds__(64) splat_blur(const uint2* __restrict__ binned,
                                                 const int* __restrict__ cur,
                                                 const _Float16* __restrict__ Gg,
                                                 _Float16* __restrict__ vox) {
    __shared__ __align__(16) _Float16 Ay[65 * 64];   // 8320 B (row 64 = OOB dummy)
    __shared__ __align__(16) _Float16 Bx[65 * 64];   // 8320 B
    int lane = threadIdx.x;
    int idx = blockIdx.x;
    int b = idx >> 6;
    int z = (idx + (b << 3)) & 63;                   // shear: balances per-CU z mix
    int q = lane >> 4, c = lane & 15;

    {   // zero tiles (single wave: LDS ops are wave-ordered)
        int4 z4 = {0, 0, 0, 0};
        int4* a4 = (int4*)Ay;
        int4* b4 = (int4*)Bx;
        for (int i = lane; i < 65 * 64 * 2 / 16; i += 64) { a4[i] = z4; b4[i] = z4; }
    }

    // G fragments: one pattern serves B-frag (pass1) & A-frag (pass2)
    half8_t gf[4][2];
#pragma unroll
    for (int ni = 0; ni < 4; ++ni)
#pragma unroll
        for (int h = 0; h < 2; ++h)
            gf[ni][h] = *(const half8_t*)&Gg[(ni * 16 + c) * 64 + h * 32 + q * 8];

    // plane z consumes bins i2=z-1 (idx z) and i2=z (idx z+1)
    int c0 = min(cur[b * NBIN + z],     CAP);
    int c1 = min(cur[b * NBIN + z + 1], CAP);
    const uint2* s0 = binned + (size_t)(b * NBIN + z) * CAP;
    const uint2* s1 = binned + (size_t)(b * NBIN + z + 1) * CAP;
    int n = c0 + c1;

    f32x4_t acc[4][4];
#pragma unroll
    for (int mi = 0; mi < 4; ++mi)
#pragma unroll
        for (int ni = 0; ni < 4; ++ni) acc[mi][ni] = (f32x4_t){0.f, 0.f, 0.f, 0.f};

    int iters = (n + 63) >> 6;
    uint2 nxt = make_uint2(0u, 0u);                 // decodes to gz=-2 -> az=0, skip
    if (lane < n) nxt = (lane < c0) ? s0[lane] : s1[lane - c0];
    for (int it = 0; it < iters; ++it) {
        uint2 pk = nxt;
        int ni2 = (it + 1) * 64 + lane;             // prefetch next chunk
        nxt = make_uint2(0u, 0u);
        if (ni2 < n) nxt = (ni2 < c0) ? s0[ni2] : s1[ni2 - c0];

        float gx = (float)(pk.x & 0xffffu) * (1.0f / FXS) - 2.0f;
        float gy = (float)(pk.x >> 16)     * (1.0f / FXS) - 2.0f;
        float gz = (float)(pk.y & 0xffffu) * (1.0f / FXS) - 2.0f;
        float f0 = floorf(gx), f1 = floorf(gy);
        int   i0 = (int)f0,    i1 = (int)f1;
        float r0 = gx - f0,    r1f = gy - f1;
        float az = fmaxf(0.0f, 1.0f - fabsf(gz - (float)z));
        int ylo = ((unsigned)i1       < 64u) ? i1       : 64;
        int yhi = ((unsigned)(i1 + 1) < 64u) ? (i1 + 1) : 64;
        int xlo = ((unsigned)i0       < 64u) ? i0       : 64;
        int xhi = ((unsigned)(i0 + 1) < 64u) ? (i0 + 1) : 64;
        Ay[swz(ylo, lane)] = (_Float16)(az * (1.0f - r1f));
        Ay[swz(yhi, lane)] = (_Float16)(az * r1f);
        Bx[swz(xlo, lane)] = (_Float16)(1.0f - r0);
        Bx[swz(xhi, lane)] = (_Float16)r0;
#pragma unroll
        for (int h = 0; h < 2; ++h) {
            half8_t af[4], bf[4];
#pragma unroll
            for (int mi = 0; mi < 4; ++mi)
                af[mi] = *(const half8_t*)&Ay[swz(mi * 16 + c, h * 32 + q * 8)];
#pragma unroll
            for (int ni = 0; ni < 4; ++ni)
                bf[ni] = *(const half8_t*)&Bx[swz(ni * 16 + c, h * 32 + q * 8)];
#pragma unroll
            for (int mi = 0; mi < 4; ++mi)
#pragma unroll
                for (int ni = 0; ni < 4; ++ni)
                    acc[mi][ni] = __builtin_amdgcn_mfma_f32_16x16x32_f16(
                        af[mi], bf[ni], acc[mi][ni], 0, 0, 0);
        }
        // re-zero exactly what we wrote (after the frag reads; wave-ordered)
        Ay[swz(ylo, lane)] = (_Float16)0.0f;
        Ay[swz(yhi, lane)] = (_Float16)0.0f;
        Bx[swz(xlo, lane)] = (_Float16)0.0f;
        Bx[swz(xhi, lane)] = (_Float16)0.0f;
    }

    asm volatile("" ::: "memory");
    _Float16* P = Ay;                                // overlay: tiles dead now
    _Float16* T = Bx;

    // clip(vox,0,1) -> f16 plane P[y][x]
#pragma unroll
    for (int mi = 0; mi < 4; ++mi)
#pragma unroll
        for (int ni = 0; ni < 4; ++ni)
#pragma unroll
            for (int r = 0; r < 4; ++r)
                P[swz(mi * 16 + q * 4 + r, ni * 16 + c)] =
                    (_Float16)fminf(fmaxf(acc[mi][ni][r], 0.0f), 1.0f);
    asm volatile("" ::: "memory");

    // pass1: Cx[y][xo] = sum_k P[y][k] * G[xo][k]
    f32x4_t a2[4][4];
#pragma unroll
    for (int mi = 0; mi < 4; ++mi)
#pragma unroll
        for (int ni = 0; ni < 4; ++ni) a2[mi][ni] = (f32x4_t){0.f, 0.f, 0.f, 0.f};
#pragma unroll
    for (int h = 0; h < 2; ++h) {
        half8_t af[4];
#pragma unroll
        for (int mi = 0; mi < 4; ++mi)
            af[mi] = *(const half8_t*)&P[swz(mi * 16 + c, h * 32 + q * 8)];
#pragma unroll
        for (int mi = 0; mi < 4; ++mi)
#pragma unroll
            for (int ni = 0; ni < 4; ++ni)
                a2[mi][ni] = __builtin_amdgcn_mfma_f32_16x16x32_f16(
                    af[mi], gf[ni][h], a2[mi][ni], 0, 0, 0);
    }
    asm volatile("" ::: "memory");

    // transpose to T[x][y] (f16), packed b64 writes
#pragma unroll
    for (int mi = 0; mi < 4; ++mi)
#pragma unroll
        for (int ni = 0; ni < 4; ++ni) {
            half4_t pkd;
#pragma unroll
            for (int r = 0; r < 4; ++r) pkd[r] = (_Float16)a2[mi][ni][r];
            *(half4_t*)&T[swz(ni * 16 + c, mi * 16 + q * 4)] = pkd;
        }
    asm volatile("" ::: "memory");

    // pass2: out[yo][x] = sum_k G[yo][k] * T[x][k]
    f32x4_t a3[4][4];
#pragma unroll
    for (int mi = 0; mi < 4; ++mi)
#pragma unroll
        for (int ni = 0; ni < 4; ++ni) a3[mi][ni] = (f32x4_t){0.f, 0.f, 0.f, 0.f};
#pragma unroll
    for (int h = 0; h < 2; ++h) {
        half8_t bf[4];
#pragma unroll
        for (int ni = 0; ni < 4; ++ni)
            bf[ni] = *(const half8_t*)&T[swz(ni * 16 + c, h * 32 + q * 8)];
#pragma unroll
        for (int mi = 0; mi < 4; ++mi)
#pragma unroll
            for (int ni = 0; ni < 4; ++ni)
                a3[mi][ni] = __builtin_amdgcn_mfma_f32_16x16x32_f16(
                    gf[mi][h], bf[ni], a3[mi][ni], 0, 0, 0);
    }

    // store f16 plane
    _Float16* dst = vox + ((size_t)b << 18) + ((size_t)z << 12);
#pragma unroll
    for (int mi = 0; mi < 4; ++mi)
#pragma unroll
        for (int ni = 0; ni < 4; ++ni)
#pragma unroll
            for (int r = 0; r < 4; ++r)
                dst[((mi * 16 + q * 4 + r) << 6) + ni * 16 + c] = (_Float16)a3[mi][ni][r];
}

// ---- 3. fused conv along z (f16 in) + scale/clip + segmented DRC + y-flip ----
__global__ void convz_drc_kernel(const _Float16* __restrict__ in,
                                 const float* __restrict__ scale,
                                 float* __restrict__ out) {
    __shared__ float sraw[640 + SZ * SZ + 640];  // 10-row zero guards each side
    __shared__ float c[SZ * SZ];
    __shared__ float segS[4][64], segT[4][64];
    float* s = sraw + 640;
    int b = blockIdx.x >> 6, y = blockIdx.x & 63;

    for (int i = threadIdx.x; i < 640; i += 256) {
        sraw[i] = 0.0f;
        sraw[640 + SZ * SZ + i] = 0.0f;
    }
    const _Float16* base = in + ((size_t)b << 18) + (y << 6);
#pragma unroll
    for (int g = 0; g < 4; ++g) {
        int cell = g * 256 + threadIdx.x;        // 1024 half4 cells
        int z = cell >> 4, xc = (cell & 15) << 2;
        half4_t v = *(const half4_t*)&base[((size_t)z << 12) + xc];
        float4 f = make_float4((float)v[0], (float)v[1], (float)v[2], (float)v[3]);
        *(float4*)&s[(z << 6) + xc] = f;
    }
    __syncthreads();

    float w[KS];
    weights_reg(w);

    {   // z-conv: one (z-group-of-4, x-chunk) per thread, 24 b128 reads
        int z0 = (threadIdx.x >> 4) << 2;
        int xc = (threadIdx.x & 15) << 2;
        float4 a0 = {0,0,0,0}, a1 = {0,0,0,0}, a2 = {0,0,0,0}, a3 = {0,0,0,0};
#pragma unroll
        for (int d = 0; d < 24; ++d) {
            int zz = z0 - HALF + d;              // guards cover [-10, 73]
            float4 v = *(const float4*)&s[(zz << 6) + xc];
            if (d <= 20)           fma4(a0, w[d],     v);
            if (d >= 1 && d <= 21) fma4(a1, w[d - 1], v);
            if (d >= 2 && d <= 22) fma4(a2, w[d - 2], v);
            if (d >= 3)            fma4(a3, w[d - 3], v);
        }
        *(float4*)&c[((z0 + 0) << 6) + xc] = a0;
        *(float4*)&c[((z0 + 1) << 6) + xc] = a1;
        *(float4*)&c[((z0 + 2) << 6) + xc] = a2;
        *(float4*)&c[((z0 + 3) << 6) + xc] = a3;
    }
    __syncthreads();

    {   // segmented DRC march: 4 z-segments x 64 columns
        int x = threadIdx.x & 63, seg = threadIdx.x >> 6;
        float sc = scale[b];
        float trans = 1.0f, sum = 0.0f;
#pragma unroll
        for (int zz = 0; zz < 16; ++zz) {
            int z = seg * 16 + zz;
            float v = fminf(fmaxf(c[(z << 6) + x] * sc, 0.0f), 1.0f);
            sum += v * trans;
            trans *= 1.0f - v;
        }
        segS[seg][x] = sum;
        segT[seg][x] = trans;
    }
    __syncthreads();
    if (threadIdx.x < 64) {
        int x = threadIdx.x;
        float t = 1.0f, S = 0.0f;
#pragma unroll
        for (int sgi = 0; sgi < 4; ++sgi) { S += segS[sgi][x] * t; t *= segT[sgi][x]; }
        out[(b << 12) + ((63 - y) << 6) + x] = S;
    }
}

extern "C" void kernel_launch(void* const* d_in, const int* in_sizes, int n_in,
                              void* d_out, int out_size, void* d_ws, size_t ws_size,
                              hipStream_t stream) {
    const float* pc    = (const float*)d_in[0];
    const float* rot   = (const float*)d_in[1];
    const float* scale = (const float*)d_in[2];
    float* out = (float*)d_out;

    // ws: vox f16 16.8 MB | binned (fixed-cap, packed) 34.1 MB | G 8 KB | cursors 8.3 KB
    _Float16* vox    = (_Float16*)d_ws;
    uint2*    binned = (uint2*)((char*)d_ws + (size_t)NB * SZ3 * sizeof(_Float16));
    _Float16* Gg     = (_Float16*)((char*)binned + (size_t)NB * NBIN * CAP * sizeof(uint2));
    int*      cur    = (int*)((char*)Gg + 64 * 64 * sizeof(_Float16));

    hipMemsetAsync(cur, 0, NB * NBIN * sizeof(int), stream);

    fill_kernel     <<<NB * NP / 1024, 256, 0, stream>>>(pc, rot, cur, binned, Gg);
    splat_blur      <<<NB * SZ, 64, 0, stream>>>(binned, cur, Gg, vox);
    convz_drc_kernel<<<NB * SZ, 256, 0, stream>>>(vox, scale, out);
}

// Round 12
// 123.306 us; speedup vs baseline: 1.1040x; 1.0238x over previous
//
#include <hip/hip_runtime.h>

#define NB    32
#define NP    65536
#define SZ    64
#define SZ3   (SZ * SZ * SZ)     // 262144
#define KS    21
#define HALF  10
#define NBIN2 130                // sub-bins: (i2+1)*2 + yhalf, i2 in [-1,63]
#define CAP2  1280               // fixed sub-bin capacity (max expected ~900)
#define FXS   960.0f             // fixed-point scale; (65+2)*960 = 64320 < 65535

typedef _Float16 half8_t __attribute__((ext_vector_type(8)));
typedef _Float16 half4_t __attribute__((ext_vector_type(4)));
typedef float    f32x4_t __attribute__((ext_vector_type(4)));

// XOR-swizzled tile address: rows x 64 cols of f16, 16B-chunk swizzle.
__device__ __forceinline__ int swz(int row, int col) {
    return (row << 6) + ((((col >> 3) ^ (row & 7))) << 3) + (col & 7);
}

// Normalized Gaussian taps (sigma=3) into registers
__device__ __forceinline__ void weights_reg(float* w) {
    float sum = 0.0f;
#pragma unroll
    for (int k = 0; k < KS; ++k) {
        float d = (float)k - (float)HALF;
        w[k] = expf(-d * d / 18.0f);
        sum += w[k];
    }
#pragma unroll
    for (int k = 0; k < KS; ++k) w[k] /= sum;
}

__device__ __forceinline__ void fma4(float4& a, float t, const float4& v) {
    a.x = fmaf(t, v.x, a.x); a.y = fmaf(t, v.y, a.y);
    a.z = fmaf(t, v.z, a.z); a.w = fmaf(t, v.w, a.w);
}

__device__ __forceinline__ unsigned pack_fx(float g) {
    float c = fminf(fmaxf(g, -2.0f), 65.0f);
    return (unsigned)__float2uint_rn((c + 2.0f) * FXS);
}

// ---- 1. fill (z, y-half) sub-bins (packed u16x4); straddlers duplicated ----
__global__ void fill_kernel(const float* __restrict__ pc,
                            const float* __restrict__ rot,
                            int* __restrict__ cur,
                            uint2* __restrict__ binned,
                            _Float16* __restrict__ Gg) {
    __shared__ int h[4][NBIN2];
    __shared__ int woff[4][NBIN2];
    __shared__ int lbase[NBIN2];
    int base = blockIdx.x * 1024;          // 4 points/thread, block within one batch
    int b = base >> 16;
    int wv = threadIdx.x >> 6;
    for (int i = threadIdx.x; i < 4 * NBIN2; i += 256) h[i / NBIN2][i % NBIN2] = 0;
    __syncthreads();
    const float* R = rot + b * 9;
    const float4* p4 = (const float4*)(pc + (size_t)base * 3);
    float4 f0 = p4[threadIdx.x * 3 + 0];
    float4 f1 = p4[threadIdx.x * 3 + 1];
    float4 f2 = p4[threadIdx.x * 3 + 2];
    float px[4] = {f0.x, f0.w, f1.z, f2.y};
    float py[4] = {f0.y, f1.x, f1.w, f2.z};
    float pz[4] = {f0.z, f1.y, f2.x, f2.w};
    uint2 pk[4];
    int bin0[4], bin1[4], lp0[4], lp1[4];
#pragma unroll
    for (int j = 0; j < 4; ++j) {
        float g0 = (R[0] * px[j] + R[1] * py[j] + R[2] * pz[j] + 0.5f) * 63.0f;
        float g1 = (R[3] * px[j] + R[4] * py[j] + R[5] * pz[j] + 0.5f) * 63.0f;
        float g2 = (R[6] * px[j] + R[7] * py[j] + R[8] * pz[j] + 0.5f) * 63.0f;
        int i2 = (int)floorf(g2);
        int i1 = (int)floorf(g1);
        bool zv = (i2 >= -1 && i2 <= 63);
        int h0 = ((unsigned)i1       < 64u) ? (i1 >> 5)       : -1;
        int h1 = ((unsigned)(i1 + 1) < 64u) ? ((i1 + 1) >> 5) : -1;
        if (h1 == h0) h1 = -1;
        bin0[j] = (zv && h0 >= 0) ? ((i2 + 1) * 2 + h0) : -1;
        bin1[j] = (zv && h1 >= 0) ? ((i2 + 1) * 2 + h1) : -1;
        pk[j] = make_uint2(pack_fx(g0) | (pack_fx(g1) << 16), pack_fx(g2));
        if (bin0[j] >= 0) lp0[j] = atomicAdd(&h[wv][bin0[j]], 1);
        if (bin1[j] >= 0) lp1[j] = atomicAdd(&h[wv][bin1[j]], 1);
    }
    __syncthreads();
    if (threadIdx.x < NBIN2) {
        int t = threadIdx.x;
        int s0 = h[0][t], s1 = h[1][t], s2 = h[2][t], s3 = h[3][t];
        int tot = s0 + s1 + s2 + s3;
        lbase[t] = tot ? atomicAdd(&cur[b * NBIN2 + t], tot) : 0;
        woff[0][t] = 0; woff[1][t] = s0; woff[2][t] = s0 + s1; woff[3][t] = s0 + s1 + s2;
    }
    __syncthreads();
#pragma unroll
    for (int j = 0; j < 4; ++j) {
        if (bin0[j] >= 0) {
            int pos = lbase[bin0[j]] + woff[wv][bin0[j]] + lp0[j];
            if (pos < CAP2)
                binned[(size_t)(b * NBIN2 + bin0[j]) * CAP2 + pos] = pk[j];
        }
        if (bin1[j] >= 0) {
            int pos = lbase[bin1[j]] + woff[wv][bin1[j]] + lp1[j];
            if (pos < CAP2)
                binned[(size_t)(b * NBIN2 + bin1[j]) * CAP2 + pos] = pk[j];
        }
    }
    // G[o][k] = g[o-k+10] (zero outside band), row-major stride 64
    if (blockIdx.x == 0) {
        float w[KS];
        weights_reg(w);
        for (int i = threadIdx.x; i < 4096; i += 256) {
            int d = (i >> 6) - (i & 63) + HALF;
            Gg[i] = ((unsigned)d < (unsigned)KS) ? (_Float16)w[d] : (_Float16)0.0f;
        }
    }
}

// ---- 2. MFMA splat + blur. TWO WAVES per (b,z): each owns one y-half. ----
// Wave w scatters its y-half's points (sub-bins) into a 33x64 A-tile and
// 65x64 B-tile, accumulating a 32x64 half-C; both waves then cooperatively
// blur the shared plane (pass1/transpose/pass2 split by output rows).
__global__ void __launch_bounds__(128) splat_blur(const uint2* __restrict__ binned,
                                                  const int* __restrict__ cur,
                                                  const _Float16* __restrict__ Gg,
                                                  _Float16* __restrict__ vox) {
    // layout: A0[0,4224) A1[4224,8448) B0[8448,16768) B1[16768,25088)
    // overlays (dead after scatter): P=[0,8192)  T=[8448,16640)
    __shared__ __align__(16) char smem[25088];
    int tid = threadIdx.x;
    int w = tid >> 6, lane = tid & 63;
    int idx = blockIdx.x;
    int b = idx >> 6;
    int k = (idx + (b << 3)) & 63;                    // shear for per-CU mix
    int z = (k & 1) ? (31 - (k >> 1)) : (32 + (k >> 1));  // center-out (LPT)
    int q = lane >> 4, c = lane & 15;

    _Float16* Ay = (_Float16*)(smem + w * 4224);      // 33 rows (32 real + dummy 32)
    _Float16* Bx = (_Float16*)(smem + 8448 + w * 8320); // 65 rows (dummy 64)
    _Float16* P  = (_Float16*)smem;
    _Float16* T  = (_Float16*)(smem + 8448);

    {   // zero own tiles (wave-local, wave-ordered)
        int4 z4 = {0, 0, 0, 0};
        int4* a4 = (int4*)Ay;
        for (int i = lane; i < 4224 / 16; i += 64) a4[i] = z4;
        int4* b4 = (int4*)Bx;
        for (int i = lane; i < 8320 / 16; i += 64) b4[i] = z4;
    }

    // G fragments (both waves load all 4; one pattern serves both passes)
    half8_t gf[4][2];
#pragma unroll
    for (int ni = 0; ni < 4; ++ni)
#pragma unroll
        for (int hh = 0; hh < 2; ++hh)
            gf[ni][hh] = *(const half8_t*)&Gg[(ni * 16 + c) * 64 + hh * 32 + q * 8];

    // this wave's sub-bins: (i2=z-1, w) and (i2=z, w)
    int c0 = min(cur[b * NBIN2 + 2 * z + w],       CAP2);
    int c1 = min(cur[b * NBIN2 + 2 * (z + 1) + w], CAP2);
    const uint2* s0 = binned + (size_t)(b * NBIN2 + 2 * z + w) * CAP2;
    const uint2* s1 = binned + (size_t)(b * NBIN2 + 2 * (z + 1) + w) * CAP2;
    int n = c0 + c1;

    f32x4_t acc[2][4];
#pragma unroll
    for (int ml = 0; ml < 2; ++ml)
#pragma unroll
        for (int ni = 0; ni < 4; ++ni) acc[ml][ni] = (f32x4_t){0.f, 0.f, 0.f, 0.f};

    int iters = (n + 63) >> 6;
    uint2 nxtA = make_uint2(0u, 0u), nxtB = make_uint2(0u, 0u);  // gz=-2 -> az=0
    {
        int i0g = lane;
        if (i0g < n) nxtA = (i0g < c0) ? s0[i0g] : s1[i0g - c0];
        int i1g = 64 + lane;
        if (i1g < n) nxtB = (i1g < c0) ? s0[i1g] : s1[i1g - c0];
    }
    for (int it = 0; it < iters; ++it) {
        uint2 pk = nxtA;
        nxtA = nxtB;
        nxtB = make_uint2(0u, 0u);
        int ni2 = (it + 2) * 64 + lane;               // prefetch depth 2
        if (ni2 < n) nxtB = (ni2 < c0) ? s0[ni2] : s1[ni2 - c0];

        float gx = (float)(pk.x & 0xffffu) * (1.0f / FXS) - 2.0f;
        float gy = (float)(pk.x >> 16)     * (1.0f / FXS) - 2.0f;
        float gz = (float)(pk.y & 0xffffu) * (1.0f / FXS) - 2.0f;
        float f0 = floorf(gx), f1 = floorf(gy);
        int   i0 = (int)f0,    i1 = (int)f1;
        float r0 = gx - f0,    r1f = gy - f1;
        float az = fmaxf(0.0f, 1.0f - fabsf(gz - (float)z));
        int rlo = i1 - (w << 5), rhi = i1 + 1 - (w << 5);
        int alo = ((unsigned)rlo < 32u) ? rlo : 32;   // dummy row 32
        int ahi = ((unsigned)rhi < 32u) ? rhi : 32;
        int xlo = ((unsigned)i0       < 64u) ? i0       : 64;
        int xhi = ((unsigned)(i0 + 1) < 64u) ? (i0 + 1) : 64;
        Ay[swz(alo, lane)] = (_Float16)(az * (1.0f - r1f));
        Ay[swz(ahi, lane)] = (_Float16)(az * r1f);
        Bx[swz(xlo, lane)] = (_Float16)(1.0f - r0);
        Bx[swz(xhi, lane)] = (_Float16)r0;
#pragma unroll
        for (int hh = 0; hh < 2; ++hh) {
            half8_t af[2], bf[4];
#pragma unroll
            for (int ml = 0; ml < 2; ++ml)
                af[ml] = *(const half8_t*)&Ay[swz(ml * 16 + c, hh * 32 + q * 8)];
#pragma unroll
            for (int ni = 0; ni < 4; ++ni)
                bf[ni] = *(const half8_t*)&Bx[swz(ni * 16 + c, hh * 32 + q * 8)];
#pragma unroll
            for (int ml = 0; ml < 2; ++ml)
#pragma unroll
                for (int ni = 0; ni < 4; ++ni)
                    acc[ml][ni] = __builtin_amdgcn_mfma_f32_16x16x32_f16(
                        af[ml], bf[ni], acc[ml][ni], 0, 0, 0);
        }
        // re-zero exactly what we wrote (after the frag reads; wave-ordered)
        Ay[swz(alo, lane)] = (_Float16)0.0f;
        Ay[swz(ahi, lane)] = (_Float16)0.0f;
        Bx[swz(xlo, lane)] = (_Float16)0.0f;
        Bx[swz(xhi, lane)] = (_Float16)0.0f;
    }

    __syncthreads();                                  // B1: all scatter done

    // each wave writes its clipped half-plane into shared P (overlay A0/A1)
#pragma unroll
    for (int ml = 0; ml < 2; ++ml)
#pragma unroll
        for (int ni = 0; ni < 4; ++ni)
#pragma unroll
            for (int r = 0; r < 4; ++r)
                P[swz((w << 5) + ml * 16 + q * 4 + r, ni * 16 + c)] =
                    (_Float16)fminf(fmaxf(acc[ml][ni][r], 0.0f), 1.0f);
    __syncthreads();                                  // B2: P complete

    // pass1 (x-blur): wave w computes output rows [32w, 32w+32)
    f32x4_t a2[2][4];
#pragma unroll
    for (int ml = 0; ml < 2; ++ml)
#pragma unroll
        for (int ni = 0; ni < 4; ++ni) a2[ml][ni] = (f32x4_t){0.f, 0.f, 0.f, 0.f};
#pragma unroll
    for (int hh = 0; hh < 2; ++hh) {
        half8_t af[2];
#pragma unroll
        for (int ml = 0; ml < 2; ++ml)
            af[ml] = *(const half8_t*)&P[swz(((w << 1) + ml) * 16 + c, hh * 32 + q * 8)];
#pragma unroll
        for (int ml = 0; ml < 2; ++ml)
#pragma unroll
            for (int ni = 0; ni < 4; ++ni)
                a2[ml][ni] = __builtin_amdgcn_mfma_f32_16x16x32_f16(
                    af[ml], gf[ni][hh], a2[ml][ni], 0, 0, 0);
    }
    // transpose into T (overlay B0); disjoint from P so no extra barrier needed
#pragma unroll
    for (int ml = 0; ml < 2; ++ml)
#pragma unroll
        for (int ni = 0; ni < 4; ++ni) {
            half4_t pkd;
#pragma unroll
            for (int r = 0; r < 4; ++r) pkd[r] = (_Float16)a2[ml][ni][r];
            *(half4_t*)&T[swz(ni * 16 + c, ((w << 1) + ml) * 16 + q * 4)] = pkd;
        }
    __syncthreads();                                  // B3: T complete

    // pass2 (y-blur): wave w computes output rows [32w, 32w+32)
    f32x4_t a3[2][4];
#pragma unroll
    for (int ml = 0; ml < 2; ++ml)
#pragma unroll
        for (int ni = 0; ni < 4; ++ni) a3[ml][ni] = (f32x4_t){0.f, 0.f, 0.f, 0.f};
#pragma unroll
    for (int hh = 0; hh < 2; ++hh) {
        half8_t bf[4];
#pragma unroll
        for (int ni = 0; ni < 4; ++ni)
            bf[ni] = *(const half8_t*)&T[swz(ni * 16 + c, hh * 32 + q * 8)];
#pragma unroll
        for (int ml = 0; ml < 2; ++ml)
#pragma unroll
            for (int ni = 0; ni < 4; ++ni)
                a3[ml][ni] = __builtin_amdgcn_mfma_f32_16x16x32_f16(
                    gf[(w << 1) + ml][hh], bf[ni], a3[ml][ni], 0, 0, 0);
    }

    // store f16 half-plane
    _Float16* dst = vox + ((size_t)b << 18) + ((size_t)z << 12);
#pragma unroll
    for (int ml = 0; ml < 2; ++ml)
#pragma unroll
        for (int ni = 0; ni < 4; ++ni)
#pragma unroll
            for (int r = 0; r < 4; ++r)
                dst[(((w << 5) + ml * 16 + q * 4 + r) << 6) + ni * 16 + c] =
                    (_Float16)a3[ml][ni][r];
}

// ---- 3. fused conv along z (f16 in) + scale/clip + segmented DRC + y-flip ----
__global__ void convz_drc_kernel(const _Float16* __restrict__ in,
                                 const float* __restrict__ scale,
                                 float* __restrict__ out) {
    __shared__ float sraw[640 + SZ * SZ + 640];  // 10-row zero guards each side
    __shared__ float c[SZ * SZ];
    __shared__ float segS[4][64], segT[4][64];
    float* s = sraw + 640;
    int b = blockIdx.x >> 6, y = blockIdx.x & 63;

    for (int i = threadIdx.x; i < 640; i += 256) {
        sraw[i] = 0.0f;
        sraw[640 + SZ * SZ + i] = 0.0f;
    }
    const _Float16* base = in + ((size_t)b << 18) + (y << 6);
#pragma unroll
    for (int g = 0; g < 4; ++g) {
        int cell = g * 256 + threadIdx.x;        // 1024 half4 cells
        int z = cell >> 4, xc = (cell & 15) << 2;
        half4_t v = *(const half4_t*)&base[((size_t)z << 12) + xc];
        float4 f = make_float4((float)v[0], (float)v[1], (float)v[2], (float)v[3]);
        *(float4*)&s[(z << 6) + xc] = f;
    }
    __syncthreads();

    float w[KS];
    weights_reg(w);

    {   // z-conv: one (z-group-of-4, x-chunk) per thread, 24 b128 reads
        int z0 = (threadIdx.x >> 4) << 2;
        int xc = (threadIdx.x & 15) << 2;
        float4 a0 = {0,0,0,0}, a1 = {0,0,0,0}, a2 = {0,0,0,0}, a3 = {0,0,0,0};
#pragma unroll
        for (int d = 0; d < 24; ++d) {
            int zz = z0 - HALF + d;              // guards cover [-10, 73]
            float4 v = *(const float4*)&s[(zz << 6) + xc];
            if (d <= 20)           fma4(a0, w[d],     v);
            if (d >= 1 && d <= 21) fma4(a1, w[d - 1], v);
            if (d >= 2 && d <= 22) fma4(a2, w[d - 2], v);
            if (d >= 3)            fma4(a3, w[d - 3], v);
        }
        *(float4*)&c[((z0 + 0) << 6) + xc] = a0;
        *(float4*)&c[((z0 + 1) << 6) + xc] = a1;
        *(float4*)&c[((z0 + 2) << 6) + xc] = a2;
        *(float4*)&c[((z0 + 3) << 6) + xc] = a3;
    }
    __syncthreads();

    {   // segmented DRC march: 4 z-segments x 64 columns
        int x = threadIdx.x & 63, seg = threadIdx.x >> 6;
        float sc = scale[b];
        float trans = 1.0f, sum = 0.0f;
#pragma unroll
        for (int zz = 0; zz < 16; ++zz) {
            int z = seg * 16 + zz;
            float v = fminf(fmaxf(c[(z << 6) + x] * sc, 0.0f), 1.0f);
            sum += v * trans;
            trans *= 1.0f - v;
        }
        segS[seg][x] = sum;
        segT[seg][x] = trans;
    }
    __syncthreads();
    if (threadIdx.x < 64) {
        int x = threadIdx.x;
        float t = 1.0f, S = 0.0f;
#pragma unroll
        for (int sgi = 0; sgi < 4; ++sgi) { S += segS[sgi][x] * t; t *= segT[sgi][x]; }
        out[(b << 12) + ((63 - y) << 6) + x] = S;
    }
}

extern "C" void kernel_launch(void* const* d_in, const int* in_sizes, int n_in,
                              void* d_out, int out_size, void* d_ws, size_t ws_size,
                              hipStream_t stream) {
    const float* pc    = (const float*)d_in[0];
    const float* rot   = (const float*)d_in[1];
    const float* scale = (const float*)d_in[2];
    float* out = (float*)d_out;

    // ws: vox f16 16.8 MB | binned sub-bins 42.6 MB | G 8 KB | cursors 16.6 KB
    _Float16* vox    = (_Float16*)d_ws;
    uint2*    binned = (uint2*)((char*)d_ws + (size_t)NB * SZ3 * sizeof(_Float16));
    _Float16* Gg     = (_Float16*)((char*)binned + (size_t)NB * NBIN2 * CAP2 * sizeof(uint2));
    int*      cur    = (int*)((char*)Gg + 64 * 64 * sizeof(_Float16));

    hipMemsetAsync(cur, 0, NB * NBIN2 * sizeof(int), stream);

    fill_kernel     <<<NB * NP / 1024, 256, 0, stream>>>(pc, rot, cur, binned, Gg);
    splat_blur      <<<NB * SZ, 128, 0, stream>>>(binned, cur, Gg, vox);
    convz_drc_kernel<<<NB * SZ, 256, 0, stream>>>(vox, scale, out);
}